// Round 15
// baseline (187.870 us; speedup 1.0000x reference)
//
#include <hip/hip_runtime.h>
#include <math.h>

#ifndef __has_builtin
#define __has_builtin(x) 0
#endif
#if __has_builtin(__builtin_amdgcn_exp2f)
#define EXP2F(x) __builtin_amdgcn_exp2f(x)
#else
#define EXP2F(x) exp2f(x)
#endif

#define L2E  1.44269504088896340736f
#define RL2E 0.69314718055994530942f

#define NBATCH 2
#define NC 21
#define NP 4096
#define KR 35
#define KS 71

typedef _Float16 half_t;
typedef _Float16 h8 __attribute__((ext_vector_type(8)));
typedef _Float16 h4 __attribute__((ext_vector_type(4)));
typedef float f4 __attribute__((ext_vector_type(4)));
typedef float f2 __attribute__((ext_vector_type(2)));
#define MFMA16(a, b, c) __builtin_amdgcn_mfma_f32_16x16x32_f16((a), (b), (c), 0, 0, 0)

// packed fp32 math via inline asm (builtin lowering NaN'd — R8/R13; asm proven R14)
static __device__ __forceinline__ f2 pk_fma(f2 a, f2 b, f2 c) {
    f2 d;
    asm volatile("v_pk_fma_f32 %0, %1, %2, %3" : "=v"(d) : "v"(a), "v"(b), "v"(c));
    return d;
}
static __device__ __forceinline__ f2 pk_add(f2 a, f2 b) {
    f2 d;
    asm volatile("v_pk_add_f32 %0, %1, %2" : "=v"(d) : "v"(a), "v"(b));
    return d;
}

// ---- tiling: occupancy push — 2048 bilat blocks, 11776 B LDS ----
#define PTILE 128          // p per block (2 m-tiles per wave)
#define NPT   32
#define SQ    32           // q-splits -> chunk = 128 q
#define CHUNK 128
#define STEPS 4            // CHUNK/32
#define NBBIL (NBATCH * NPT * SQ)   // 2048
#define NBCONV (NBATCH * NC)        // 42
#define SEGS_PER_S 1024
#define SEG_HALVES 256

// ---- ws layout (float offsets) ----
#define OFF_QFEAT 0                  // [NB*P][8] fp32 AoS {L*f0..L*f4, h, 0,0}
#define OFF_QSOA  65536              // [6][NB*P] fp32 SoA planes
#define OFF_UT    114688             // [NB*P][24] fp32 log-unary
#define OFF_QSF   311296             // [NB][21][P] fp32 spatial out
#define OFF_G     483328             // [64][64] fp16 band-gaussian
#define OFF_QH16  485376             // [NB][24][P] fp16 planar q
#define OFF_PART  845824             // [SQ][1024 segs][256] fp16 partials (16.8 MB)

// ---- LDS: bilat 11776 B (SoA 3072 + qls 8704); conv kernel separate 27648 ----
#define QLS_STRIDE 136     // halves (128 data + 8 pad); stride 68 words ≡ 4 mod 32

__global__ __launch_bounds__(256) void setup_kernel(
    const float* __restrict__ unary, const float* __restrict__ ref,
    const float* __restrict__ kstd, float* __restrict__ ws,
    float* __restrict__ outq)
{
    int gid = blockIdx.x * 256 + threadIdx.x;
    if (gid < 4096) {
        float s = 0.f;
        for (int t = -KR; t <= KR; ++t) s += expf(-(float)(t * t) * (1.0f / 72.0f));
        int y = gid >> 6, yp = gid & 63;
        int d = y - yp;
        float v = (d >= -KR && d <= KR) ? expf(-(float)(d * d) * (1.0f / 72.0f)) / s : 0.f;
        ((half_t*)(ws + OFF_G))[gid] = (half_t)v;
    }
    if (gid >= NBATCH * NP) return;
    int n = gid >> 12, p = gid & (NP - 1);
    int y = p >> 6, x = p & 63;
    float k0 = kstd[0], k1 = kstd[1], k2 = kstd[2], k3 = kstd[3], k4 = kstd[4];
    const float* rp = ref + n * 3 * NP + p;
    float f0 = (float)y / k0;
    float f1 = (float)x / k1;
    float f2_ = rp[0]      / k2;
    float f3 = rp[NP]     / k3;
    float f4_ = rp[2 * NP] / k4;
    float sq = f0*f0 + f1*f1 + f2_*f2_ + f3*f3 + f4_*f4_;
    float h  = -0.5f * L2E * sq;       // exp2 exponent offset
    float* qf = ws + OFF_QFEAT + gid * 8;
    qf[0]=L2E*f0; qf[1]=L2E*f1; qf[2]=L2E*f2_; qf[3]=L2E*f3; qf[4]=L2E*f4_;
    qf[5]=h; qf[6]=0.f; qf[7]=0.f;
    float* qs = ws + OFF_QSOA;
    qs[0*8192 + gid] = L2E*f0;  qs[1*8192 + gid] = L2E*f1;
    qs[2*8192 + gid] = L2E*f2_; qs[3*8192 + gid] = L2E*f3;
    qs[4*8192 + gid] = L2E*f4_; qs[5*8192 + gid] = h;

    float U[NC], e[NC];
    const float* up = unary + n * NC * NP + p;
    float m = -1e30f;
    for (int c = 0; c < NC; ++c) {
        float u = up[c * NP];
        u = fminf(fmaxf(u, 1e-5f), 1.0f);
        U[c] = logf(u);
        m = fmaxf(m, U[c]);
    }
    float ssum = 0.f;
    for (int c = 0; c < NC; ++c) { e[c] = EXP2F(L2E * (U[c] - m)); ssum += e[c]; }
    float inv = 1.0f / ssum;
    float* ut = ws + OFF_UT + gid * 24;
    half_t* qh = (half_t*)(ws + OFF_QH16);
    for (int c = 0; c < NC; ++c) {
        float qv = e[c] * inv;
        ut[c] = U[c];
        qh[(n * 24 + c) * NP + p] = (half_t)qv;
        outq[(n * NC + c) * NP + p] = qv;
    }
    ut[21] = 0.f; ut[22] = 0.f; ut[23] = 0.f;
    qh[(n * 24 + 21) * NP + p] = (half_t)0.f;
    qh[(n * 24 + 22) * NP + p] = (half_t)0.f;
    qh[(n * 24 + 23) * NP + p] = (half_t)0.f;
}

// ---- separable conv as its own kernel (R14-proven code, 42 blocks) ----
__global__ __launch_bounds__(256) void conv_kernel(
    const half_t* __restrict__ qh16,
    const half_t* __restrict__ gmat,
    float* __restrict__ qsf)
{
    __shared__ __align__(16) char lds[27648];
    int b = blockIdx.x;
    int tid = threadIdx.x;
    int l = tid & 63, w = tid >> 6;
    int n = b / NC, c = b % NC;
    half_t* qt = (half_t*)lds;
    half_t* gl = (half_t*)(lds + 9216);
    half_t* dl = (half_t*)(lds + 18432);

    for (int i = tid; i < 512; i += 256) {
        int row = i >> 3, g = i & 7;
        *(h8*)(gl + row * 72 + g * 8) = *(const h8*)(gmat + row * 64 + g * 8);
    }
    const half_t* qsrc = qh16 + (size_t)(n * 24 + c) * NP;
    for (int i = tid; i < 512; i += 256) {
        int row = i >> 3, g = i & 7;
        h8 v = *(const h8*)(qsrc + row * 64 + g * 8);
        #pragma unroll
        for (int k = 0; k < 8; ++k) qt[(g * 8 + k) * 72 + row] = v[k];
    }
    __syncthreads();

    int m0 = w * 16;
    f4 acc1[4];
    #pragma unroll
    for (int nt = 0; nt < 4; ++nt) acc1[nt] = (f4)0.f;
    #pragma unroll
    for (int ks = 0; ks < 2; ++ks) {
        h8 af = *(const h8*)(gl + (size_t)(m0 + (l & 15)) * 72 + ks * 32 + (l >> 4) * 8);
        #pragma unroll
        for (int nt = 0; nt < 4; ++nt) {
            h8 bf = *(const h8*)(qt + (size_t)(nt * 16 + (l & 15)) * 72 + ks * 32 + (l >> 4) * 8);
            acc1[nt] = MFMA16(af, bf, acc1[nt]);
        }
    }
    #pragma unroll
    for (int nt = 0; nt < 4; ++nt)
        #pragma unroll
        for (int r = 0; r < 4; ++r)
            dl[(size_t)(m0 + (l >> 4) * 4 + r) * 72 + nt * 16 + (l & 15)] = (half_t)acc1[nt][r];
    __syncthreads();

    f4 acc2[4];
    #pragma unroll
    for (int nt = 0; nt < 4; ++nt) acc2[nt] = (f4)0.f;
    #pragma unroll
    for (int ks = 0; ks < 2; ++ks) {
        h8 af = *(const h8*)(dl + (size_t)(m0 + (l & 15)) * 72 + ks * 32 + (l >> 4) * 8);
        #pragma unroll
        for (int nt = 0; nt < 4; ++nt) {
            h8 bf = *(const h8*)(gl + (size_t)(nt * 16 + (l & 15)) * 72 + ks * 32 + (l >> 4) * 8);
            acc2[nt] = MFMA16(af, bf, acc2[nt]);
        }
    }
    float* dst = qsf + (size_t)(n * NC + c) * NP;
    #pragma unroll
    for (int nt = 0; nt < 4; ++nt)
        #pragma unroll
        for (int r = 0; r < 4; ++r)
            dst[(size_t)(m0 + (l >> 4) * 4 + r) * 64 + nt * 16 + (l & 15)] = acc2[nt][r];
}

// ---- bilateral: 2048 blocks, chunk=128, LDS 11776 B ----
__global__ __launch_bounds__(256) void bilat_kernel(
    const float* __restrict__ qfeatA,     // AoS (p side)
    const float* __restrict__ qsoa,       // SoA planes (q side)
    const half_t* __restrict__ qh16,
    half_t* __restrict__ part)
{
    __shared__ __align__(16) char lds[11776];
    int b = blockIdx.x;
    int tid = threadIdx.x;
    int l = tid & 63, w = tid >> 6;

    int n  = b & 1;
    int pt = (b >> 1) & (NPT - 1);
    int s  = b >> 6;                           // 0..31
    float*  qsoaS = (float*)lds;               // [6][128]  3072 B
    half_t* qls   = (half_t*)(lds + 3072);     // [32][136] 8704 B

    // stage SoA q-features (coalesced per plane): 192 float4
    for (int i = tid; i < 192; i += 256) {
        int d = i >> 5, g = i & 31;
        *(f4*)(qsoaS + d * CHUNK + g * 4) =
            *(const f4*)(qsoa + (size_t)d * 8192 + n * NP + s * CHUNK + g * 4);
    }
    // stage q-probs fp16 rows 0..20 (336 h8); zero rows 21..31 (187 h8)
    for (int i = tid; i < 21 * 16; i += 256) {
        int c = i >> 4, g = i & 15;
        *(h8*)(qls + c * QLS_STRIDE + g * 8) =
            *(const h8*)(qh16 + (size_t)(n * 24 + c) * NP + s * CHUNK + g * 8);
    }
    for (int i = tid; i < 11 * 17; i += 256) {
        int c = 21 + i / 17, g = i % 17;
        *(h8*)(qls + c * QLS_STRIDE + g * 8) = (h8)(half_t)0.f;
    }
    // p-side features: wave w owns m-tiles w*2, w*2+1; lane row = l&15
    f2 pf2[2][5], ph2[2];
    #pragma unroll
    for (int mt = 0; mt < 2; ++mt) {
        const float* fp = qfeatA + (size_t)(n * NP + pt * PTILE + (w * 2 + mt) * 16 + (l & 15)) * 8;
        #pragma unroll
        for (int i = 0; i < 5; ++i) {
            float v = fp[i] * RL2E;
            pf2[mt][i] = (f2){v, v};
        }
        ph2[mt] = (f2){fp[5], fp[5]};
    }
    f4 acc[2][2];
    #pragma unroll
    for (int mt = 0; mt < 2; ++mt) { acc[mt][0] = (f4)0.f; acc[mt][1] = (f4)0.f; }
    int kq = (l >> 4) * 8;
    __syncthreads();

    for (int step = 0; step < STEPS; ++step) {
        int qbase = step * 32 + kq;
        h8 kv[2];
        #pragma unroll
        for (int hf = 0; hf < 2; ++hf) {
            f4 qf0 = *(const f4*)(qsoaS + 0 * CHUNK + qbase + hf * 4);
            f4 qf1 = *(const f4*)(qsoaS + 1 * CHUNK + qbase + hf * 4);
            f4 qf2 = *(const f4*)(qsoaS + 2 * CHUNK + qbase + hf * 4);
            f4 qf3 = *(const f4*)(qsoaS + 3 * CHUNK + qbase + hf * 4);
            f4 qf4 = *(const f4*)(qsoaS + 4 * CHUNK + qbase + hf * 4);
            f4 qf5 = *(const f4*)(qsoaS + 5 * CHUNK + qbase + hf * 4);
            #pragma unroll
            for (int pr = 0; pr < 2; ++pr) {
                f2 q0 = {qf0[2*pr], qf0[2*pr+1]};
                f2 q1 = {qf1[2*pr], qf1[2*pr+1]};
                f2 q2 = {qf2[2*pr], qf2[2*pr+1]};
                f2 q3 = {qf3[2*pr], qf3[2*pr+1]};
                f2 q4 = {qf4[2*pr], qf4[2*pr+1]};
                f2 qh2 = {qf5[2*pr], qf5[2*pr+1]};
                #pragma unroll
                for (int mt = 0; mt < 2; ++mt) {
                    f2 e = pk_add(qh2, ph2[mt]);
                    e = pk_fma(pf2[mt][0], q0, e);
                    e = pk_fma(pf2[mt][1], q1, e);
                    e = pk_fma(pf2[mt][2], q2, e);
                    e = pk_fma(pf2[mt][3], q3, e);
                    e = pk_fma(pf2[mt][4], q4, e);
                    kv[mt][hf * 4 + pr * 2]     = (half_t)EXP2F(e[0]);
                    kv[mt][hf * 4 + pr * 2 + 1] = (half_t)EXP2F(e[1]);
                }
            }
        }
        h8 bf0 = *(const h8*)(qls + (size_t)(l & 15) * QLS_STRIDE + qbase);
        h8 bf1 = *(const h8*)(qls + (size_t)(16 + (l & 15)) * QLS_STRIDE + qbase);
        #pragma unroll
        for (int mt = 0; mt < 2; ++mt) {
            acc[mt][0] = MFMA16(kv[mt], bf0, acc[mt][0]);
            acc[mt][1] = MFMA16(kv[mt], bf1, acc[mt][1]);
        }
    }
    // epilogue: raw C-fragment partials, fp16, coalesced b64
    #pragma unroll
    for (int mt = 0; mt < 2; ++mt) {
        #pragma unroll
        for (int cht = 0; cht < 2; ++cht) {
            int segFlat = ((((s * 2 + n) * NPT + pt) * 4 + w) * 2 + mt) * 2 + cht;
            h4 hv;
            hv[0] = (half_t)acc[mt][cht][0];
            hv[1] = (half_t)acc[mt][cht][1];
            hv[2] = (half_t)acc[mt][cht][2];
            hv[3] = (half_t)acc[mt][cht][3];
            *(h4*)(part + (size_t)segFlat * SEG_HALVES + l * 4) = hv;
        }
    }
}

// L2+L3 merged: reduce fp16 partials over s (32 slices), then softmax update.
// 64 blocks, one per (n, pt)
__global__ __launch_bounds__(256) void reduce_update_kernel(
    const half_t* __restrict__ part, const float* __restrict__ ut_,
    const float* __restrict__ qsf, float* __restrict__ outq,
    half_t* __restrict__ qh16)
{
    __shared__ float red[4096];    // 16 segs * 256
    int rb = blockIdx.x;           // [0,64)
    int tid = threadIdx.x;
    int n = rb & 1, pt = rb >> 1;

    float acc[16];
    #pragma unroll
    for (int k = 0; k < 16; ++k) acc[k] = 0.f;
    for (int s = 0; s < SQ; ++s) {
        size_t base = (size_t)(((s * 2 + n) * NPT + pt) * 16) * SEG_HALVES;
        #pragma unroll
        for (int k = 0; k < 4; ++k) {
            h4 v = *(const h4*)(part + base + (size_t)(k * 256 + tid) * 4);
            acc[k*4+0] += (float)v[0]; acc[k*4+1] += (float)v[1];
            acc[k*4+2] += (float)v[2]; acc[k*4+3] += (float)v[3];
        }
    }
    #pragma unroll
    for (int k = 0; k < 4; ++k)
        *(f4*)(red + (k * 256 + tid) * 4) =
            (f4){acc[k*4+0], acc[k*4+1], acc[k*4+2], acc[k*4+3]};
    __syncthreads();

    if (tid < PTILE) {
        int pp = tid;
        int p = pt * PTILE + pp;
        int gid = n * NP + p;
        int mt_g = pp >> 4;                // 0..7
        int wv = mt_g >> 1, mtl = mt_g & 1;
        int mrow = pp & 15;
        int lg = mrow >> 2, reg = mrow & 3;
        int segL = wv * 4 + mtl * 2;       // + cht

        float lg_[NC], e[NC];
        const float* ut = ut_ + (size_t)gid * 24;
        const float* qs = qsf + (size_t)n * NC * NP + p;
        float m = -1e30f;
        #pragma unroll
        for (int c = 0; c < NC; ++c) {
            int cht = c >> 4, chL = c & 15;
            float qb = red[(segL + cht) * 256 + (lg * 16 + chL) * 4 + reg];
            float li = ut[c] + 4.0f * qb + 2.0f * qs[c * NP];
            lg_[c] = li;
            m = fmaxf(m, li);
        }
        float ssum = 0.f;
        #pragma unroll
        for (int c = 0; c < NC; ++c) { e[c] = EXP2F(L2E * (lg_[c] - m)); ssum += e[c]; }
        float inv = 1.0f / ssum;
        #pragma unroll
        for (int c = 0; c < NC; ++c) {
            float qv = e[c] * inv;
            outq[(size_t)(n * NC + c) * NP + p] = qv;
            qh16[(size_t)(n * 24 + c) * NP + p] = (half_t)qv;
        }
    }
}

extern "C" void kernel_launch(void* const* d_in, const int* in_sizes, int n_in,
                              void* d_out, int out_size, void* d_ws, size_t ws_size,
                              hipStream_t stream)
{
    const float* unary = (const float*)d_in[0];
    const float* ref   = (const float*)d_in[1];
    const float* kstd  = (const float*)d_in[3];
    float* ws   = (float*)d_ws;
    float* outq = (float*)d_out;

    const float*  qfeatA = ws + OFF_QFEAT;
    const float*  qsoa   = ws + OFF_QSOA;
    float*        ut     = ws + OFF_UT;
    float*        qsf    = ws + OFF_QSF;
    const half_t* gmat   = (const half_t*)(ws + OFF_G);
    half_t*       qh16   = (half_t*)(ws + OFF_QH16);
    half_t*       part   = (half_t*)(ws + OFF_PART);

    setup_kernel<<<32, 256, 0, stream>>>(unary, ref, kstd, ws, outq);
    for (int it = 0; it < 5; ++it) {
        conv_kernel<<<NBCONV, 256, 0, stream>>>(qh16, gmat, qsf);
        bilat_kernel<<<NBBIL, 256, 0, stream>>>(qfeatA, qsoa, qh16, part);
        reduce_update_kernel<<<64, 256, 0, stream>>>(part, ut, qsf, outq, qh16);
    }
}

// Round 16
// 169.482 us; speedup vs baseline: 1.1085x; 1.1085x over previous
//
#include <hip/hip_runtime.h>
#include <math.h>

#ifndef __has_builtin
#define __has_builtin(x) 0
#endif
#if __has_builtin(__builtin_amdgcn_exp2f)
#define EXP2F(x) __builtin_amdgcn_exp2f(x)
#else
#define EXP2F(x) exp2f(x)
#endif

#define L2E  1.44269504088896340736f
#define RL2E 0.69314718055994530942f

#define NBATCH 2
#define NC 21
#define NP 4096
#define KR 35
#define KS 71

typedef _Float16 half_t;
typedef _Float16 h8 __attribute__((ext_vector_type(8)));
typedef _Float16 h4 __attribute__((ext_vector_type(4)));
typedef float f4 __attribute__((ext_vector_type(4)));
typedef float f2 __attribute__((ext_vector_type(2)));
#define MFMA16(a, b, c) __builtin_amdgcn_mfma_f32_16x16x32_f16((a), (b), (c), 0, 0, 0)

// packed fp32 math via inline asm (builtin lowering NaN'd — R8/R13; asm proven R14)
static __device__ __forceinline__ f2 pk_fma(f2 a, f2 b, f2 c) {
    f2 d;
    asm volatile("v_pk_fma_f32 %0, %1, %2, %3" : "=v"(d) : "v"(a), "v"(b), "v"(c));
    return d;
}
static __device__ __forceinline__ f2 pk_add(f2 a, f2 b) {
    f2 d;
    asm volatile("v_pk_add_f32 %0, %1, %2" : "=v"(d) : "v"(a), "v"(b));
    return d;
}

// ---- tiling: R14-proven (best measured: 155.5 us) ----
#define PTILE 128          // p per block (2 m-tiles per wave)
#define NPT   32
#define SQ    16           // q-splits -> chunk = 256 q
#define CHUNK 256
#define STEPS 8            // CHUNK/32
#define NBBIL (NBATCH * NPT * SQ)   // 1024
#define NBCONV (NBATCH * NC)        // 42
#define SEGS_PER_S 1024
#define SEG_HALVES 256

// ---- ws layout (float offsets) ----
#define OFF_QFEAT 0                  // [NB*P][8] fp32 AoS {L*f0..L*f4, h, 0,0}
#define OFF_QSOA  65536              // [6][NB*P] fp32 SoA planes
#define OFF_UT    114688             // [NB*P][24] fp32 log-unary
#define OFF_QSF   311296             // [NB][21][P] fp32 spatial out
#define OFF_G     483328             // [64][64] fp16 band-gaussian
#define OFF_QH16  485376             // [NB][24][P] fp16 planar q
#define OFF_PART  845824             // [SQ][1024 segs][256] fp16 partials (8.4 MB)
#define OFF_KF    2942976            // K fragments: 33,554,432 halves (67 MB)

// ---- LDS: 27648 B (conv path needs it; bilat/gemm use less) ----
#define LDS_BYTES 27648
#define QLS_STRIDE 264     // halves (256 data + 8 pad) — R6-proven banking

__global__ __launch_bounds__(256) void setup_kernel(
    const float* __restrict__ unary, const float* __restrict__ ref,
    const float* __restrict__ kstd, float* __restrict__ ws,
    float* __restrict__ outq)
{
    int gid = blockIdx.x * 256 + threadIdx.x;
    if (gid < 4096) {
        float s = 0.f;
        for (int t = -KR; t <= KR; ++t) s += expf(-(float)(t * t) * (1.0f / 72.0f));
        int y = gid >> 6, yp = gid & 63;
        int d = y - yp;
        float v = (d >= -KR && d <= KR) ? expf(-(float)(d * d) * (1.0f / 72.0f)) / s : 0.f;
        ((half_t*)(ws + OFF_G))[gid] = (half_t)v;
    }
    if (gid >= NBATCH * NP) return;
    int n = gid >> 12, p = gid & (NP - 1);
    int y = p >> 6, x = p & 63;
    float k0 = kstd[0], k1 = kstd[1], k2 = kstd[2], k3 = kstd[3], k4 = kstd[4];
    const float* rp = ref + n * 3 * NP + p;
    float f0 = (float)y / k0;
    float f1 = (float)x / k1;
    float f2_ = rp[0]      / k2;
    float f3 = rp[NP]     / k3;
    float f4_ = rp[2 * NP] / k4;
    float sq = f0*f0 + f1*f1 + f2_*f2_ + f3*f3 + f4_*f4_;
    float h  = -0.5f * L2E * sq;       // exp2 exponent offset
    float* qf = ws + OFF_QFEAT + gid * 8;
    qf[0]=L2E*f0; qf[1]=L2E*f1; qf[2]=L2E*f2_; qf[3]=L2E*f3; qf[4]=L2E*f4_;
    qf[5]=h; qf[6]=0.f; qf[7]=0.f;
    float* qs = ws + OFF_QSOA;
    qs[0*8192 + gid] = L2E*f0;  qs[1*8192 + gid] = L2E*f1;
    qs[2*8192 + gid] = L2E*f2_; qs[3*8192 + gid] = L2E*f3;
    qs[4*8192 + gid] = L2E*f4_; qs[5*8192 + gid] = h;

    float U[NC], e[NC];
    const float* up = unary + n * NC * NP + p;
    float m = -1e30f;
    for (int c = 0; c < NC; ++c) {
        float u = up[c * NP];
        u = fminf(fmaxf(u, 1e-5f), 1.0f);
        U[c] = logf(u);
        m = fmaxf(m, U[c]);
    }
    float ssum = 0.f;
    for (int c = 0; c < NC; ++c) { e[c] = EXP2F(L2E * (U[c] - m)); ssum += e[c]; }
    float inv = 1.0f / ssum;
    float* ut = ws + OFF_UT + gid * 24;
    half_t* qh = (half_t*)(ws + OFF_QH16);
    for (int c = 0; c < NC; ++c) {
        float qv = e[c] * inv;
        ut[c] = U[c];
        qh[(n * 24 + c) * NP + p] = (half_t)qv;
        outq[(n * NC + c) * NP + p] = qv;
    }
    ut[21] = 0.f; ut[22] = 0.f; ut[23] = 0.f;
    qh[(n * 24 + 21) * NP + p] = (half_t)0.f;
    qh[(n * 24 + 22) * NP + p] = (half_t)0.f;
    qh[(n * 24 + 23) * NP + p] = (half_t)0.f;
}

// shared conv body (G*Q*G via MFMA) — R14-proven
static __device__ __forceinline__ void conv_body(
    char* lds, int cb, int tid, int l, int w,
    const half_t* __restrict__ qh16, const half_t* __restrict__ gmat,
    float* __restrict__ qsf)
{
    int n = cb / NC, c = cb % NC;
    half_t* qt = (half_t*)lds;
    half_t* gl = (half_t*)(lds + 9216);
    half_t* dl = (half_t*)(lds + 18432);

    for (int i = tid; i < 512; i += 256) {
        int row = i >> 3, g = i & 7;
        *(h8*)(gl + row * 72 + g * 8) = *(const h8*)(gmat + row * 64 + g * 8);
    }
    const half_t* qsrc = qh16 + (size_t)(n * 24 + c) * NP;
    for (int i = tid; i < 512; i += 256) {
        int row = i >> 3, g = i & 7;
        h8 v = *(const h8*)(qsrc + row * 64 + g * 8);
        #pragma unroll
        for (int k = 0; k < 8; ++k) qt[(g * 8 + k) * 72 + row] = v[k];
    }
    __syncthreads();

    int m0 = w * 16;
    f4 acc1[4];
    #pragma unroll
    for (int nt = 0; nt < 4; ++nt) acc1[nt] = (f4)0.f;
    #pragma unroll
    for (int ks = 0; ks < 2; ++ks) {
        h8 af = *(const h8*)(gl + (size_t)(m0 + (l & 15)) * 72 + ks * 32 + (l >> 4) * 8);
        #pragma unroll
        for (int nt = 0; nt < 4; ++nt) {
            h8 bf = *(const h8*)(qt + (size_t)(nt * 16 + (l & 15)) * 72 + ks * 32 + (l >> 4) * 8);
            acc1[nt] = MFMA16(af, bf, acc1[nt]);
        }
    }
    #pragma unroll
    for (int nt = 0; nt < 4; ++nt)
        #pragma unroll
        for (int r = 0; r < 4; ++r)
            dl[(size_t)(m0 + (l >> 4) * 4 + r) * 72 + nt * 16 + (l & 15)] = (half_t)acc1[nt][r];
    __syncthreads();

    f4 acc2[4];
    #pragma unroll
    for (int nt = 0; nt < 4; ++nt) acc2[nt] = (f4)0.f;
    #pragma unroll
    for (int ks = 0; ks < 2; ++ks) {
        h8 af = *(const h8*)(dl + (size_t)(m0 + (l & 15)) * 72 + ks * 32 + (l >> 4) * 8);
        #pragma unroll
        for (int nt = 0; nt < 4; ++nt) {
            h8 bf = *(const h8*)(gl + (size_t)(nt * 16 + (l & 15)) * 72 + ks * 32 + (l >> 4) * 8);
            acc2[nt] = MFMA16(af, bf, acc2[nt]);
        }
    }
    float* dst = qsf + (size_t)(n * NC + c) * NP;
    #pragma unroll
    for (int nt = 0; nt < 4; ++nt)
        #pragma unroll
        for (int r = 0; r < 4; ++r)
            dst[(size_t)(m0 + (l >> 4) * 4 + r) * 64 + nt * 16 + (l & 15)] = acc2[nt][r];
}

// L1 iter 0: R14 bilateral + spill K fragments to kf.  [1024,1066): conv.
__global__ __launch_bounds__(256) void bilat_conv_kernel(
    const float* __restrict__ qfeatA,
    const float* __restrict__ qsoa,
    const half_t* __restrict__ qh16,
    const half_t* __restrict__ gmat,
    half_t* __restrict__ part,
    float* __restrict__ qsf,
    half_t* __restrict__ kf)
{
    __shared__ __align__(16) char lds[LDS_BYTES];
    int b = blockIdx.x;
    int tid = threadIdx.x;
    int l = tid & 63, w = tid >> 6;

    if (b < NBBIL) {
        int n  = b & 1;
        int pt = (b >> 1) & (NPT - 1);
        int s  = b >> 6;                           // 0..15
        float*  qsoaS = (float*)lds;               // [6][256]  6 KB
        half_t* qls   = (half_t*)(lds + 6144);     // [32][264] 16896 B

        for (int i = tid; i < 6 * (CHUNK / 4); i += 256) {
            int d = i >> 6, g = i & 63;
            *(f4*)(qsoaS + d * CHUNK + g * 4) =
                *(const f4*)(qsoa + (size_t)d * 8192 + n * NP + s * CHUNK + g * 4);
        }
        for (int i = tid; i < 21 * (CHUNK / 8); i += 256) {
            int c = i >> 5, g = i & 31;
            *(h8*)(qls + c * QLS_STRIDE + g * 8) =
                *(const h8*)(qh16 + (size_t)(n * 24 + c) * NP + s * CHUNK + g * 8);
        }
        for (int i = tid; i < 11 * 33; i += 256) {
            int c = 21 + i / 33, g = i % 33;
            *(h8*)(qls + c * QLS_STRIDE + g * 8) = (h8)(half_t)0.f;
        }
        f2 pf2[2][5], ph2[2];
        #pragma unroll
        for (int mt = 0; mt < 2; ++mt) {
            const float* fp = qfeatA + (size_t)(n * NP + pt * PTILE + (w * 2 + mt) * 16 + (l & 15)) * 8;
            #pragma unroll
            for (int i = 0; i < 5; ++i) {
                float v = fp[i] * RL2E;
                pf2[mt][i] = (f2){v, v};
            }
            ph2[mt] = (f2){fp[5], fp[5]};
        }
        f4 acc[2][2];
        #pragma unroll
        for (int mt = 0; mt < 2; ++mt) { acc[mt][0] = (f4)0.f; acc[mt][1] = (f4)0.f; }
        int kq = (l >> 4) * 8;
        __syncthreads();

        for (int step = 0; step < STEPS; ++step) {
            int qbase = step * 32 + kq;
            h8 kv[2];
            #pragma unroll
            for (int hf = 0; hf < 2; ++hf) {
                f4 qf0 = *(const f4*)(qsoaS + 0 * CHUNK + qbase + hf * 4);
                f4 qf1 = *(const f4*)(qsoaS + 1 * CHUNK + qbase + hf * 4);
                f4 qf2 = *(const f4*)(qsoaS + 2 * CHUNK + qbase + hf * 4);
                f4 qf3 = *(const f4*)(qsoaS + 3 * CHUNK + qbase + hf * 4);
                f4 qf4 = *(const f4*)(qsoaS + 4 * CHUNK + qbase + hf * 4);
                f4 qf5 = *(const f4*)(qsoaS + 5 * CHUNK + qbase + hf * 4);
                #pragma unroll
                for (int pr = 0; pr < 2; ++pr) {
                    f2 q0 = {qf0[2*pr], qf0[2*pr+1]};
                    f2 q1 = {qf1[2*pr], qf1[2*pr+1]};
                    f2 q2 = {qf2[2*pr], qf2[2*pr+1]};
                    f2 q3 = {qf3[2*pr], qf3[2*pr+1]};
                    f2 q4 = {qf4[2*pr], qf4[2*pr+1]};
                    f2 qh2 = {qf5[2*pr], qf5[2*pr+1]};
                    #pragma unroll
                    for (int mt = 0; mt < 2; ++mt) {
                        f2 e = pk_add(qh2, ph2[mt]);
                        e = pk_fma(pf2[mt][0], q0, e);
                        e = pk_fma(pf2[mt][1], q1, e);
                        e = pk_fma(pf2[mt][2], q2, e);
                        e = pk_fma(pf2[mt][3], q3, e);
                        e = pk_fma(pf2[mt][4], q4, e);
                        kv[mt][hf * 4 + pr * 2]     = (half_t)EXP2F(e[0]);
                        kv[mt][hf * 4 + pr * 2 + 1] = (half_t)EXP2F(e[1]);
                    }
                }
            }
            // spill K fragments for iters 2-5 (exact fp16 values used below)
            int qstep = s * STEPS + step;              // 0..127
            #pragma unroll
            for (int mt = 0; mt < 2; ++mt) {
                int pt16 = pt * 8 + w * 2 + mt;        // 0..255
                *(h8*)(kf + ((size_t)(n * 256 + pt16) * 128 + qstep) * 512 + l * 8) = kv[mt];
            }
            h8 bf0 = *(const h8*)(qls + (size_t)(l & 15) * QLS_STRIDE + qbase);
            h8 bf1 = *(const h8*)(qls + (size_t)(16 + (l & 15)) * QLS_STRIDE + qbase);
            #pragma unroll
            for (int mt = 0; mt < 2; ++mt) {
                acc[mt][0] = MFMA16(kv[mt], bf0, acc[mt][0]);
                acc[mt][1] = MFMA16(kv[mt], bf1, acc[mt][1]);
            }
        }
        #pragma unroll
        for (int mt = 0; mt < 2; ++mt) {
            #pragma unroll
            for (int cht = 0; cht < 2; ++cht) {
                int segFlat = ((((s * 2 + n) * NPT + pt) * 4 + w) * 2 + mt) * 2 + cht;
                h4 hv;
                hv[0] = (half_t)acc[mt][cht][0];
                hv[1] = (half_t)acc[mt][cht][1];
                hv[2] = (half_t)acc[mt][cht][2];
                hv[3] = (half_t)acc[mt][cht][3];
                *(h4*)(part + (size_t)segFlat * SEG_HALVES + l * 4) = hv;
            }
        }
    } else {
        conv_body(lds, b - NBBIL, tid, l, w, qh16, gmat, qsf);
    }
}

// L1 iters 2-5: stream kf (L3-resident) through MFMA.  [1024,1066): conv.
__global__ __launch_bounds__(256) void gemm_conv_kernel(
    const half_t* __restrict__ kf,
    const half_t* __restrict__ qh16,
    const half_t* __restrict__ gmat,
    half_t* __restrict__ part,
    float* __restrict__ qsf)
{
    __shared__ __align__(16) char lds[LDS_BYTES];
    int b = blockIdx.x;
    int tid = threadIdx.x;
    int l = tid & 63, w = tid >> 6;

    if (b < NBBIL) {
        int n  = b & 1;
        int pt = (b >> 1) & (NPT - 1);
        int s  = b >> 6;                           // 0..15
        half_t* qls = (half_t*)lds;                // [32][264] 16896 B

        for (int i = tid; i < 21 * (CHUNK / 8); i += 256) {
            int c = i >> 5, g = i & 31;
            *(h8*)(qls + c * QLS_STRIDE + g * 8) =
                *(const h8*)(qh16 + (size_t)(n * 24 + c) * NP + s * CHUNK + g * 8);
        }
        for (int i = tid; i < 11 * 33; i += 256) {
            int c = 21 + i / 33, g = i % 33;
            *(h8*)(qls + c * QLS_STRIDE + g * 8) = (h8)(half_t)0.f;
        }
        f4 acc[2][2];
        #pragma unroll
        for (int mt = 0; mt < 2; ++mt) { acc[mt][0] = (f4)0.f; acc[mt][1] = (f4)0.f; }
        int kq = (l >> 4) * 8;
        int pt16b = pt * 8 + w * 2;                // base m-tile
        const half_t* kf0 = kf + ((size_t)(n * 256 + pt16b) * 128 + s * STEPS) * 512 + l * 8;
        const half_t* kf1 = kf0 + (size_t)128 * 512;   // mt=1 tile row
        __syncthreads();

        // register prefetch across steps
        h8 av0 = *(const h8*)(kf0);
        h8 av1 = *(const h8*)(kf1);
        for (int step = 0; step < STEPS; ++step) {
            int qbase = step * 32 + kq;
            h8 cur0 = av0, cur1 = av1;
            if (step < STEPS - 1) {
                av0 = *(const h8*)(kf0 + (size_t)(step + 1) * 512);
                av1 = *(const h8*)(kf1 + (size_t)(step + 1) * 512);
            }
            h8 bf0 = *(const h8*)(qls + (size_t)(l & 15) * QLS_STRIDE + qbase);
            h8 bf1 = *(const h8*)(qls + (size_t)(16 + (l & 15)) * QLS_STRIDE + qbase);
            acc[0][0] = MFMA16(cur0, bf0, acc[0][0]);
            acc[0][1] = MFMA16(cur0, bf1, acc[0][1]);
            acc[1][0] = MFMA16(cur1, bf0, acc[1][0]);
            acc[1][1] = MFMA16(cur1, bf1, acc[1][1]);
        }
        #pragma unroll
        for (int mt = 0; mt < 2; ++mt) {
            #pragma unroll
            for (int cht = 0; cht < 2; ++cht) {
                int segFlat = ((((s * 2 + n) * NPT + pt) * 4 + w) * 2 + mt) * 2 + cht;
                h4 hv;
                hv[0] = (half_t)acc[mt][cht][0];
                hv[1] = (half_t)acc[mt][cht][1];
                hv[2] = (half_t)acc[mt][cht][2];
                hv[3] = (half_t)acc[mt][cht][3];
                *(h4*)(part + (size_t)segFlat * SEG_HALVES + l * 4) = hv;
            }
        }
    } else {
        conv_body(lds, b - NBBIL, tid, l, w, qh16, gmat, qsf);
    }
}

// L2+L3 merged (R14-proven): 64 blocks, one per (n, pt)
__global__ __launch_bounds__(256) void reduce_update_kernel(
    const half_t* __restrict__ part, const float* __restrict__ ut_,
    const float* __restrict__ qsf, float* __restrict__ outq,
    half_t* __restrict__ qh16)
{
    __shared__ float red[4096];    // 16 segs * 256
    int rb = blockIdx.x;           // [0,64)
    int tid = threadIdx.x;
    int n = rb & 1, pt = rb >> 1;

    float acc[16];
    #pragma unroll
    for (int k = 0; k < 16; ++k) acc[k] = 0.f;
    for (int s = 0; s < SQ; ++s) {
        size_t base = (size_t)(((s * 2 + n) * NPT + pt) * 16) * SEG_HALVES;
        #pragma unroll
        for (int k = 0; k < 4; ++k) {
            h4 v = *(const h4*)(part + base + (size_t)(k * 256 + tid) * 4);
            acc[k*4+0] += (float)v[0]; acc[k*4+1] += (float)v[1];
            acc[k*4+2] += (float)v[2]; acc[k*4+3] += (float)v[3];
        }
    }
    #pragma unroll
    for (int k = 0; k < 4; ++k)
        *(f4*)(red + (k * 256 + tid) * 4) =
            (f4){acc[k*4+0], acc[k*4+1], acc[k*4+2], acc[k*4+3]};
    __syncthreads();

    if (tid < PTILE) {
        int pp = tid;
        int p = pt * PTILE + pp;
        int gid = n * NP + p;
        int mt_g = pp >> 4;                // 0..7
        int wv = mt_g >> 1, mtl = mt_g & 1;
        int mrow = pp & 15;
        int lg = mrow >> 2, reg = mrow & 3;
        int segL = wv * 4 + mtl * 2;       // + cht

        float lg_[NC], e[NC];
        const float* ut = ut_ + (size_t)gid * 24;
        const float* qs = qsf + (size_t)n * NC * NP + p;
        float m = -1e30f;
        #pragma unroll
        for (int c = 0; c < NC; ++c) {
            int cht = c >> 4, chL = c & 15;
            float qb = red[(segL + cht) * 256 + (lg * 16 + chL) * 4 + reg];
            float li = ut[c] + 4.0f * qb + 2.0f * qs[c * NP];
            lg_[c] = li;
            m = fmaxf(m, li);
        }
        float ssum = 0.f;
        #pragma unroll
        for (int c = 0; c < NC; ++c) { e[c] = EXP2F(L2E * (lg_[c] - m)); ssum += e[c]; }
        float inv = 1.0f / ssum;
        #pragma unroll
        for (int c = 0; c < NC; ++c) {
            float qv = e[c] * inv;
            outq[(size_t)(n * NC + c) * NP + p] = qv;
            qh16[(size_t)(n * 24 + c) * NP + p] = (half_t)qv;
        }
    }
}

extern "C" void kernel_launch(void* const* d_in, const int* in_sizes, int n_in,
                              void* d_out, int out_size, void* d_ws, size_t ws_size,
                              hipStream_t stream)
{
    const float* unary = (const float*)d_in[0];
    const float* ref   = (const float*)d_in[1];
    const float* kstd  = (const float*)d_in[3];
    float* ws   = (float*)d_ws;
    float* outq = (float*)d_out;

    const float*  qfeatA = ws + OFF_QFEAT;
    const float*  qsoa   = ws + OFF_QSOA;
    float*        ut     = ws + OFF_UT;
    float*        qsf    = ws + OFF_QSF;
    const half_t* gmat   = (const half_t*)(ws + OFF_G);
    half_t*       qh16   = (half_t*)(ws + OFF_QH16);
    half_t*       part   = (half_t*)(ws + OFF_PART);
    half_t*       kf     = (half_t*)(ws + OFF_KF);

    setup_kernel<<<32, 256, 0, stream>>>(unary, ref, kstd, ws, outq);
    // iter 1: compute K once (R14 path) and persist fragments
    bilat_conv_kernel<<<NBBIL + NBCONV, 256, 0, stream>>>(
        qfeatA, qsoa, qh16, gmat, part, qsf, kf);
    reduce_update_kernel<<<64, 256, 0, stream>>>(part, ut, qsf, outq, qh16);
    // iters 2-5: stream persisted K through MFMA
    for (int it = 1; it < 5; ++it) {
        gemm_conv_kernel<<<NBBIL + NBCONV, 256, 0, stream>>>(
            kf, qh16, gmat, part, qsf);
        reduce_update_kernel<<<64, 256, 0, stream>>>(part, ut, qsf, outq, qh16);
    }
}

// Round 17
// 155.716 us; speedup vs baseline: 1.2065x; 1.0884x over previous
//
#include <hip/hip_runtime.h>
#include <math.h>

#ifndef __has_builtin
#define __has_builtin(x) 0
#endif
#if __has_builtin(__builtin_amdgcn_exp2f)
#define EXP2F(x) __builtin_amdgcn_exp2f(x)
#else
#define EXP2F(x) exp2f(x)
#endif

#define L2E  1.44269504088896340736f
#define RL2E 0.69314718055994530942f

#define NBATCH 2
#define NC 21
#define NP 4096
#define KR 35
#define KS 71

typedef _Float16 half_t;
typedef _Float16 h8 __attribute__((ext_vector_type(8)));
typedef _Float16 h4 __attribute__((ext_vector_type(4)));
typedef float f4 __attribute__((ext_vector_type(4)));
typedef float f2 __attribute__((ext_vector_type(2)));
#define MFMA16(a, b, c) __builtin_amdgcn_mfma_f32_16x16x32_f16((a), (b), (c), 0, 0, 0)

// packed fp32 math via inline asm (builtin lowering NaN'd — R8/R13; asm proven R14)
static __device__ __forceinline__ f2 pk_fma(f2 a, f2 b, f2 c) {
    f2 d;
    asm volatile("v_pk_fma_f32 %0, %1, %2, %3" : "=v"(d) : "v"(a), "v"(b), "v"(c));
    return d;
}
static __device__ __forceinline__ f2 pk_add(f2 a, f2 b) {
    f2 d;
    asm volatile("v_pk_add_f32 %0, %1, %2" : "=v"(d) : "v"(a), "v"(b));
    return d;
}

// ---- tiling: R14-proven optimum (155.5 us) ----
#define PTILE 128          // p per block (2 m-tiles per wave)
#define NPT   32
#define SQ    16           // q-splits -> chunk = 256 q
#define CHUNK 256
#define STEPS 8            // CHUNK/32
#define NBBIL (NBATCH * NPT * SQ)   // 1024
#define NBCONV (NBATCH * NC)        // 42
#define SEGS_PER_S 1024
#define SEG_HALVES 256

// ---- ws layout (float offsets) ----
#define OFF_QFEAT 0                  // [NB*P][8] fp32 AoS {L*f0..L*f4, h, 0,0}
#define OFF_QSOA  65536              // [6][NB*P] fp32 SoA planes
#define OFF_UT    114688             // [NB*P][24] fp32 log-unary
#define OFF_QSF   311296             // [NB][21][P] fp32 spatial out
#define OFF_G     483328             // [64][64] fp16 band-gaussian
#define OFF_QH16  485376             // [NB][24][P] fp16 planar q
#define OFF_PART  845824             // [SQ][1024 segs][256] fp16 partials

// ---- LDS: bilat 23040 B (SoA 6144 + qls 16896), conv 27648 B ----
#define LDS_BYTES 27648
#define QLS_STRIDE 264     // halves (256 data + 8 pad) — R6-proven banking

__global__ __launch_bounds__(256) void setup_kernel(
    const float* __restrict__ unary, const float* __restrict__ ref,
    const float* __restrict__ kstd, float* __restrict__ ws,
    float* __restrict__ outq)
{
    int gid = blockIdx.x * 256 + threadIdx.x;
    if (gid < 4096) {
        float s = 0.f;
        for (int t = -KR; t <= KR; ++t) s += expf(-(float)(t * t) * (1.0f / 72.0f));
        int y = gid >> 6, yp = gid & 63;
        int d = y - yp;
        float v = (d >= -KR && d <= KR) ? expf(-(float)(d * d) * (1.0f / 72.0f)) / s : 0.f;
        ((half_t*)(ws + OFF_G))[gid] = (half_t)v;
    }
    if (gid >= NBATCH * NP) return;
    int n = gid >> 12, p = gid & (NP - 1);
    int y = p >> 6, x = p & 63;
    float k0 = kstd[0], k1 = kstd[1], k2 = kstd[2], k3 = kstd[3], k4 = kstd[4];
    const float* rp = ref + n * 3 * NP + p;
    float f0 = (float)y / k0;
    float f1 = (float)x / k1;
    float f2_ = rp[0]      / k2;
    float f3 = rp[NP]     / k3;
    float f4_ = rp[2 * NP] / k4;
    float sq = f0*f0 + f1*f1 + f2_*f2_ + f3*f3 + f4_*f4_;
    float h  = -0.5f * L2E * sq;       // exp2 exponent offset
    float* qf = ws + OFF_QFEAT + gid * 8;
    qf[0]=L2E*f0; qf[1]=L2E*f1; qf[2]=L2E*f2_; qf[3]=L2E*f3; qf[4]=L2E*f4_;
    qf[5]=h; qf[6]=0.f; qf[7]=0.f;
    float* qs = ws + OFF_QSOA;
    qs[0*8192 + gid] = L2E*f0;  qs[1*8192 + gid] = L2E*f1;
    qs[2*8192 + gid] = L2E*f2_; qs[3*8192 + gid] = L2E*f3;
    qs[4*8192 + gid] = L2E*f4_; qs[5*8192 + gid] = h;

    float U[NC], e[NC];
    const float* up = unary + n * NC * NP + p;
    float m = -1e30f;
    for (int c = 0; c < NC; ++c) {
        float u = up[c * NP];
        u = fminf(fmaxf(u, 1e-5f), 1.0f);
        U[c] = logf(u);
        m = fmaxf(m, U[c]);
    }
    float ssum = 0.f;
    for (int c = 0; c < NC; ++c) { e[c] = EXP2F(L2E * (U[c] - m)); ssum += e[c]; }
    float inv = 1.0f / ssum;
    float* ut = ws + OFF_UT + gid * 24;
    half_t* qh = (half_t*)(ws + OFF_QH16);
    for (int c = 0; c < NC; ++c) {
        float qv = e[c] * inv;
        ut[c] = U[c];
        qh[(n * 24 + c) * NP + p] = (half_t)qv;
        outq[(n * NC + c) * NP + p] = qv;
    }
    ut[21] = 0.f; ut[22] = 0.f; ut[23] = 0.f;
    qh[(n * 24 + 21) * NP + p] = (half_t)0.f;
    qh[(n * 24 + 22) * NP + p] = (half_t)0.f;
    qh[(n * 24 + 23) * NP + p] = (half_t)0.f;
}

// L1: blocks [0,1024): bilateral.  blocks [1024,1066): separable conv.
__global__ __launch_bounds__(256) void bilat_conv_kernel(
    const float* __restrict__ qfeatA,     // AoS (p side)
    const float* __restrict__ qsoa,       // SoA planes (q side)
    const half_t* __restrict__ qh16,
    const half_t* __restrict__ gmat,
    half_t* __restrict__ part,
    float* __restrict__ qsf)
{
    __shared__ __align__(16) char lds[LDS_BYTES];
    int b = blockIdx.x;
    int tid = threadIdx.x;
    int l = tid & 63, w = tid >> 6;

    if (b < NBBIL) {
        int n  = b & 1;
        int pt = (b >> 1) & (NPT - 1);
        int s  = b >> 6;                           // 0..15
        float*  qsoaS = (float*)lds;               // [6][256]  6 KB
        half_t* qls   = (half_t*)(lds + 6144);     // [32][264] 16896 B

        // stage SoA q-features (coalesced per plane)
        for (int i = tid; i < 6 * (CHUNK / 4); i += 256) {   // 384 float4
            int d = i >> 6, g = i & 63;
            *(f4*)(qsoaS + d * CHUNK + g * 4) =
                *(const f4*)(qsoa + (size_t)d * 8192 + n * NP + s * CHUNK + g * 4);
        }
        // stage q-probs fp16 rows 0..20; zero rows 21..31
        for (int i = tid; i < 21 * (CHUNK / 8); i += 256) {  // 672 h8
            int c = i >> 5, g = i & 31;
            *(h8*)(qls + c * QLS_STRIDE + g * 8) =
                *(const h8*)(qh16 + (size_t)(n * 24 + c) * NP + s * CHUNK + g * 8);
        }
        for (int i = tid; i < 11 * 33; i += 256) {           // 363 h8 zeros
            int c = 21 + i / 33, g = i % 33;
            *(h8*)(qls + c * QLS_STRIDE + g * 8) = (h8)(half_t)0.f;
        }
        // p-side features: wave w owns m-tiles w*2, w*2+1; lane row = l&15
        // broadcast pairs hoisted for packed math
        f2 pf2[2][5], ph2[2];
        #pragma unroll
        for (int mt = 0; mt < 2; ++mt) {
            const float* fp = qfeatA + (size_t)(n * NP + pt * PTILE + (w * 2 + mt) * 16 + (l & 15)) * 8;
            #pragma unroll
            for (int i = 0; i < 5; ++i) {
                float v = fp[i] * RL2E;
                pf2[mt][i] = (f2){v, v};
            }
            ph2[mt] = (f2){fp[5], fp[5]};
        }
        f4 acc[2][2];
        #pragma unroll
        for (int mt = 0; mt < 2; ++mt) { acc[mt][0] = (f4)0.f; acc[mt][1] = (f4)0.f; }
        int kq = (l >> 4) * 8;
        __syncthreads();

        for (int step = 0; step < STEPS; ++step) {
            int qbase = step * 32 + kq;
            h8 kv[2];
            #pragma unroll
            for (int hf = 0; hf < 2; ++hf) {
                // conflict-free b128 quad reads: this lane's 4 q's, all 6 features
                f4 qf0 = *(const f4*)(qsoaS + 0 * CHUNK + qbase + hf * 4);
                f4 qf1 = *(const f4*)(qsoaS + 1 * CHUNK + qbase + hf * 4);
                f4 qf2 = *(const f4*)(qsoaS + 2 * CHUNK + qbase + hf * 4);
                f4 qf3 = *(const f4*)(qsoaS + 3 * CHUNK + qbase + hf * 4);
                f4 qf4 = *(const f4*)(qsoaS + 4 * CHUNK + qbase + hf * 4);
                f4 qf5 = *(const f4*)(qsoaS + 5 * CHUNK + qbase + hf * 4);
                // packed fp32 fma via asm: two q's per instruction
                #pragma unroll
                for (int pr = 0; pr < 2; ++pr) {
                    f2 q0 = {qf0[2*pr], qf0[2*pr+1]};
                    f2 q1 = {qf1[2*pr], qf1[2*pr+1]};
                    f2 q2 = {qf2[2*pr], qf2[2*pr+1]};
                    f2 q3 = {qf3[2*pr], qf3[2*pr+1]};
                    f2 q4 = {qf4[2*pr], qf4[2*pr+1]};
                    f2 qh2 = {qf5[2*pr], qf5[2*pr+1]};
                    #pragma unroll
                    for (int mt = 0; mt < 2; ++mt) {
                        f2 e = pk_add(qh2, ph2[mt]);
                        e = pk_fma(pf2[mt][0], q0, e);
                        e = pk_fma(pf2[mt][1], q1, e);
                        e = pk_fma(pf2[mt][2], q2, e);
                        e = pk_fma(pf2[mt][3], q3, e);
                        e = pk_fma(pf2[mt][4], q4, e);
                        kv[mt][hf * 4 + pr * 2]     = (half_t)EXP2F(e[0]);
                        kv[mt][hf * 4 + pr * 2 + 1] = (half_t)EXP2F(e[1]);
                    }
                }
            }
            h8 bf0 = *(const h8*)(qls + (size_t)(l & 15) * QLS_STRIDE + qbase);
            h8 bf1 = *(const h8*)(qls + (size_t)(16 + (l & 15)) * QLS_STRIDE + qbase);
            #pragma unroll
            for (int mt = 0; mt < 2; ++mt) {
                acc[mt][0] = MFMA16(kv[mt], bf0, acc[mt][0]);
                acc[mt][1] = MFMA16(kv[mt], bf1, acc[mt][1]);
            }
        }
        // epilogue: raw C-fragment partials, fp16, coalesced b64
        #pragma unroll
        for (int mt = 0; mt < 2; ++mt) {
            #pragma unroll
            for (int cht = 0; cht < 2; ++cht) {
                int segFlat = ((((s * 2 + n) * NPT + pt) * 4 + w) * 2 + mt) * 2 + cht;
                h4 hv;
                hv[0] = (half_t)acc[mt][cht][0];
                hv[1] = (half_t)acc[mt][cht][1];
                hv[2] = (half_t)acc[mt][cht][2];
                hv[3] = (half_t)acc[mt][cht][3];
                *(h4*)(part + (size_t)segFlat * SEG_HALVES + l * 4) = hv;
            }
        }
    } else {
        // ---- conv block: one (n,c); qsf = G * Q * G ----
        int cb = b - NBBIL;
        int n = cb / NC, c = cb % NC;
        half_t* qt = (half_t*)lds;
        half_t* gl = (half_t*)(lds + 9216);
        half_t* dl = (half_t*)(lds + 18432);

        for (int i = tid; i < 512; i += 256) {
            int row = i >> 3, g = i & 7;
            *(h8*)(gl + row * 72 + g * 8) = *(const h8*)(gmat + row * 64 + g * 8);
        }
        const half_t* qsrc = qh16 + (size_t)(n * 24 + c) * NP;
        for (int i = tid; i < 512; i += 256) {
            int row = i >> 3, g = i & 7;
            h8 v = *(const h8*)(qsrc + row * 64 + g * 8);
            #pragma unroll
            for (int k = 0; k < 8; ++k) qt[(g * 8 + k) * 72 + row] = v[k];
        }
        __syncthreads();

        int m0 = w * 16;
        f4 acc1[4];
        #pragma unroll
        for (int nt = 0; nt < 4; ++nt) acc1[nt] = (f4)0.f;
        #pragma unroll
        for (int ks = 0; ks < 2; ++ks) {
            h8 af = *(const h8*)(gl + (size_t)(m0 + (l & 15)) * 72 + ks * 32 + (l >> 4) * 8);
            #pragma unroll
            for (int nt = 0; nt < 4; ++nt) {
                h8 bf = *(const h8*)(qt + (size_t)(nt * 16 + (l & 15)) * 72 + ks * 32 + (l >> 4) * 8);
                acc1[nt] = MFMA16(af, bf, acc1[nt]);
            }
        }
        #pragma unroll
        for (int nt = 0; nt < 4; ++nt)
            #pragma unroll
            for (int r = 0; r < 4; ++r)
                dl[(size_t)(m0 + (l >> 4) * 4 + r) * 72 + nt * 16 + (l & 15)] = (half_t)acc1[nt][r];
        __syncthreads();

        f4 acc2[4];
        #pragma unroll
        for (int nt = 0; nt < 4; ++nt) acc2[nt] = (f4)0.f;
        #pragma unroll
        for (int ks = 0; ks < 2; ++ks) {
            h8 af = *(const h8*)(dl + (size_t)(m0 + (l & 15)) * 72 + ks * 32 + (l >> 4) * 8);
            #pragma unroll
            for (int nt = 0; nt < 4; ++nt) {
                h8 bf = *(const h8*)(gl + (size_t)(nt * 16 + (l & 15)) * 72 + ks * 32 + (l >> 4) * 8);
                acc2[nt] = MFMA16(af, bf, acc2[nt]);
            }
        }
        float* dst = qsf + (size_t)(n * NC + c) * NP;
        #pragma unroll
        for (int nt = 0; nt < 4; ++nt)
            #pragma unroll
            for (int r = 0; r < 4; ++r)
                dst[(size_t)(m0 + (l >> 4) * 4 + r) * 64 + nt * 16 + (l & 15)] = acc2[nt][r];
    }
}

// L2+L3 merged: reduce fp16 partials over s, then per-pixel softmax update.
// 64 blocks, one per (n, pt): 16 consecutive segments per s-slice.
__global__ __launch_bounds__(256) void reduce_update_kernel(
    const half_t* __restrict__ part, const float* __restrict__ ut_,
    const float* __restrict__ qsf, float* __restrict__ outq,
    half_t* __restrict__ qh16)
{
    __shared__ float red[4096];    // 16 segs * 256
    int rb = blockIdx.x;           // [0,64)
    int tid = threadIdx.x;
    int n = rb & 1, pt = rb >> 1;

    float acc[16];
    #pragma unroll
    for (int k = 0; k < 16; ++k) acc[k] = 0.f;
    for (int s = 0; s < SQ; ++s) {
        size_t base = (size_t)(((s * 2 + n) * NPT + pt) * 16) * SEG_HALVES;
        #pragma unroll
        for (int k = 0; k < 4; ++k) {
            h4 v = *(const h4*)(part + base + (size_t)(k * 256 + tid) * 4);
            acc[k*4+0] += (float)v[0]; acc[k*4+1] += (float)v[1];
            acc[k*4+2] += (float)v[2]; acc[k*4+3] += (float)v[3];
        }
    }
    #pragma unroll
    for (int k = 0; k < 4; ++k)
        *(f4*)(red + (k * 256 + tid) * 4) =
            (f4){acc[k*4+0], acc[k*4+1], acc[k*4+2], acc[k*4+3]};
    __syncthreads();

    if (tid < PTILE) {
        int pp = tid;
        int p = pt * PTILE + pp;
        int gid = n * NP + p;
        int mt_g = pp >> 4;                // 0..7
        int wv = mt_g >> 1, mtl = mt_g & 1;
        int mrow = pp & 15;
        int lg = mrow >> 2, reg = mrow & 3;
        int segL = wv * 4 + mtl * 2;       // + cht

        float lg_[NC], e[NC];
        const float* ut = ut_ + (size_t)gid * 24;
        const float* qs = qsf + (size_t)n * NC * NP + p;
        float m = -1e30f;
        #pragma unroll
        for (int c = 0; c < NC; ++c) {
            int cht = c >> 4, chL = c & 15;
            float qb = red[(segL + cht) * 256 + (lg * 16 + chL) * 4 + reg];
            float li = ut[c] + 4.0f * qb + 2.0f * qs[c * NP];
            lg_[c] = li;
            m = fmaxf(m, li);
        }
        float ssum = 0.f;
        #pragma unroll
        for (int c = 0; c < NC; ++c) { e[c] = EXP2F(L2E * (lg_[c] - m)); ssum += e[c]; }
        float inv = 1.0f / ssum;
        #pragma unroll
        for (int c = 0; c < NC; ++c) {
            float qv = e[c] * inv;
            outq[(size_t)(n * NC + c) * NP + p] = qv;
            qh16[(size_t)(n * 24 + c) * NP + p] = (half_t)qv;
        }
    }
}

extern "C" void kernel_launch(void* const* d_in, const int* in_sizes, int n_in,
                              void* d_out, int out_size, void* d_ws, size_t ws_size,
                              hipStream_t stream)
{
    const float* unary = (const float*)d_in[0];
    const float* ref   = (const float*)d_in[1];
    const float* kstd  = (const float*)d_in[3];
    float* ws   = (float*)d_ws;
    float* outq = (float*)d_out;

    const float*  qfeatA = ws + OFF_QFEAT;
    const float*  qsoa   = ws + OFF_QSOA;
    float*        ut     = ws + OFF_UT;
    float*        qsf    = ws + OFF_QSF;
    const half_t* gmat   = (const half_t*)(ws + OFF_G);
    half_t*       qh16   = (half_t*)(ws + OFF_QH16);
    half_t*       part   = (half_t*)(ws + OFF_PART);

    setup_kernel<<<32, 256, 0, stream>>>(unary, ref, kstd, ws, outq);
    for (int it = 0; it < 5; ++it) {
        bilat_conv_kernel<<<NBBIL + NBCONV, 256, 0, stream>>>(
            qfeatA, qsoa, qh16, gmat, part, qsf);
        reduce_update_kernel<<<64, 256, 0, stream>>>(part, ut, qsf, outq, qh16);
    }
}